// Round 1
// baseline (1236.032 us; speedup 1.0000x reference)
//
#include <hip/hip_runtime.h>
#include <stdint.h>

typedef float f32x4 __attribute__((ext_vector_type(4)));
typedef __bf16 bf16x8 __attribute__((ext_vector_type(8)));

#define SEQ 50
#define TDEC 60

static __device__ __forceinline__ float ex2(float x) { return __builtin_amdgcn_exp2f(x); }
static __device__ __forceinline__ float frcp_(float x) { return __builtin_amdgcn_rcpf(x); }
static __device__ __forceinline__ __bf16 bfc(float x) { return (__bf16)x; }

// Block: 256 threads (4 waves), owns 64 batch rows for the full sequence.
// Wave w owns hidden-slice u in [16w, 16w+16) => gate n-tiles {w, w+4, w+8, w+12}.
// h LDS layout frag-major: [kc][mt][quad][m16][8] so A-frag read addr = base + lane*16.
__global__ __launch_bounds__(256, 1) void lstm_s2s(
    const float* __restrict__ hist,
    const float* __restrict__ eWih0, const float* __restrict__ eWhh0,
    const float* __restrict__ ebih0, const float* __restrict__ ebhh0,
    const float* __restrict__ eWih1, const float* __restrict__ eWhh1,
    const float* __restrict__ ebih1, const float* __restrict__ ebhh1,
    const float* __restrict__ dWih0, const float* __restrict__ dWhh0,
    const float* __restrict__ dbih0, const float* __restrict__ dbhh0,
    const float* __restrict__ dWih1, const float* __restrict__ dWhh1,
    const float* __restrict__ dbih1, const float* __restrict__ dbhh1,
    const float* __restrict__ linW, const float* __restrict__ linb,
    const float* __restrict__ stok,
    float* __restrict__ out)
{
  __shared__ __bf16 xbuf[SEQ * 64 * 8];   // [t][row][8] (IN=6 padded to 8, k-chunk0 only)
  __shared__ __bf16 hb0[4096];            // [kc][mt][q][m16][8]
  __shared__ __bf16 hb1[4096];
  __shared__ __bf16 obuf[64 * 8];         // [row][8] decoder feedback (OUT=2 padded)

  const int tid = threadIdx.x;
  const int lane = tid & 63;
  const int w = tid >> 6;        // wave id 0..3
  const int c = lane & 15;       // col within 16-tile
  const int q = lane >> 4;       // quad
  const long rowbase = (long)blockIdx.x * 64;

  bf16x8 zfrag;
#pragma unroll
  for (int j = 0; j < 8; ++j) zfrag[j] = (__bf16)0.0f;

  // ---- stage ego history (agent 0) into LDS as bf16 ----
  {
    const float* eg = hist + rowbase * 3000;  // 3000 = A*S*IN floats per batch row
    for (int i = tid; i < 64 * 300; i += 256) {
      int row = i / 300;
      int o = i - row * 300;          // = t*6 + k, contiguous
      int t = o / 6;
      int k = o - t * 6;
      xbuf[(t * 64 + row) * 8 + k] = bfc(eg[row * 3000 + o]);
    }
    for (int i = tid; i < 64 * SEQ; i += 256) {
      xbuf[i * 8 + 6] = (__bf16)0.0f;
      xbuf[i * 8 + 7] = (__bf16)0.0f;
    }
    for (int i = tid; i < 2048; i += 256) {
      ((unsigned int*)hb0)[i] = 0u;
      ((unsigned int*)hb1)[i] = 0u;
    }
  }

  // fold log2(e) scales into weights/biases: gates i,f,o feed sigmoid (need -x*log2e),
  // gate g feeds tanh (need +2x*log2e).
  const float GS[4] = {-1.442695041f, -1.442695041f, 2.885390082f, -1.442695041f};

  bf16x8 wxL0[4];                        // padded K=32 input-weight B-frags (layer0)
  bf16x8 whL0[4][2], wxL1[4][2], whL1[4][2];
  float bs0[4], bs1[4];

  auto loadFull = [&](const float* W, bf16x8 (*dst)[2]) {
#pragma unroll
    for (int g = 0; g < 4; ++g)
#pragma unroll
      for (int kc = 0; kc < 2; ++kc) {
        const float* p = W + ((g * 4 + w) * 16 + c) * 64 + kc * 32 + q * 8;
        f32x4 a = *(const f32x4*)p;
        f32x4 b = *(const f32x4*)(p + 4);
        bf16x8 f;
        f[0] = bfc(GS[g] * a[0]); f[1] = bfc(GS[g] * a[1]);
        f[2] = bfc(GS[g] * a[2]); f[3] = bfc(GS[g] * a[3]);
        f[4] = bfc(GS[g] * b[0]); f[5] = bfc(GS[g] * b[1]);
        f[6] = bfc(GS[g] * b[2]); f[7] = bfc(GS[g] * b[3]);
        dst[g][kc] = f;
      }
  };
  auto loadPad = [&](const float* W, int Kin, bf16x8* dst) {
#pragma unroll
    for (int g = 0; g < 4; ++g) {
      bf16x8 f = zfrag;
      if (q == 0) {
        const float* p = W + ((g * 4 + w) * 16 + c) * Kin;
        for (int j = 0; j < Kin; ++j) f[j] = bfc(GS[g] * p[j]);
      }
      dst[g] = f;
    }
  };
  auto loadBias = [&](const float* bi, const float* bh, float* bs) {
#pragma unroll
    for (int g = 0; g < 4; ++g) {
      int n = g * 64 + w * 16 + c;
      bs[g] = GS[g] * (bi[n] + bh[n]);
    }
  };

  // h-write address constant for this lane (C-layout -> frag-major LDS)
  const int u = w * 16 + c;
  const int wconst = (u >> 5) * 2048 + ((u >> 3) & 3) * 128 + q * 32 + (u & 7);

  float cs0[16], cs1[16];
#pragma unroll
  for (int i = 0; i < 16; ++i) { cs0[i] = 0.0f; cs1[i] = 0.0f; }

  // elementwise LSTM update + h write (gates pre-scaled by GS)
  auto epilogue = [&](f32x4 (*acc)[4], __bf16* hb, float* cs) {
    __syncthreads();   // everyone done reading old h before overwrite
#pragma unroll
    for (int mt = 0; mt < 4; ++mt)
#pragma unroll
      for (int r = 0; r < 4; ++r) {
        float eI = ex2(acc[0][mt][r]);   // e^{-i}
        float eF = ex2(acc[1][mt][r]);   // e^{-f}
        float eG = ex2(acc[2][mt][r]);   // e^{2g}
        float eO = ex2(acc[3][mt][r]);   // e^{-o}
        float cc = cs[mt * 4 + r];
        float c2 = frcp_(1.0f + eF) * cc +
                   (eG - 1.0f) * frcp_((1.0f + eI) * (eG + 1.0f));
        float eC = ex2(2.885390082f * c2);
        float h2 = (eC - 1.0f) * frcp_((1.0f + eO) * (eC + 1.0f));
        cs[mt * 4 + r] = c2;
        hb[wconst + mt * 512 + r * 8] = bfc(h2);
      }
    __syncthreads();
  };

  // cell with full-K (64) x input read from an h-buffer
  auto cellF = [&](const __bf16* xsrc, const bf16x8 (*wx)[2], const bf16x8 (*wh)[2],
                   __bf16* hb, const float* bs, float* cs) {
    f32x4 acc[4][4];
#pragma unroll
    for (int g = 0; g < 4; ++g) {
      float b = bs[g];
#pragma unroll
      for (int mt = 0; mt < 4; ++mt) {
        acc[g][mt][0] = b; acc[g][mt][1] = b; acc[g][mt][2] = b; acc[g][mt][3] = b;
      }
    }
#pragma unroll
    for (int kc = 0; kc < 2; ++kc)
#pragma unroll
      for (int mt = 0; mt < 4; ++mt) {
        bf16x8 xf = *(const bf16x8*)(xsrc + (kc * 4 + mt) * 512 + lane * 8);
#pragma unroll
        for (int g = 0; g < 4; ++g)
          acc[g][mt] = __builtin_amdgcn_mfma_f32_16x16x32_bf16(xf, wx[g][kc], acc[g][mt], 0, 0, 0);
      }
#pragma unroll
    for (int kc = 0; kc < 2; ++kc)
#pragma unroll
      for (int mt = 0; mt < 4; ++mt) {
        bf16x8 hf = *(const bf16x8*)(hb + (kc * 4 + mt) * 512 + lane * 8);
#pragma unroll
        for (int g = 0; g < 4; ++g)
          acc[g][mt] = __builtin_amdgcn_mfma_f32_16x16x32_bf16(hf, wh[g][kc], acc[g][mt], 0, 0, 0);
      }
    epilogue(acc, hb, cs);
  };

  // cell with small padded x input (one K=32 chunk, data in quad 0 only)
  auto cellP = [&](const __bf16* xsrc, int t, const bf16x8* wxp, const bf16x8 (*wh)[2],
                   __bf16* hb, const float* bs, float* cs) {
    f32x4 acc[4][4];
#pragma unroll
    for (int g = 0; g < 4; ++g) {
      float b = bs[g];
#pragma unroll
      for (int mt = 0; mt < 4; ++mt) {
        acc[g][mt][0] = b; acc[g][mt][1] = b; acc[g][mt][2] = b; acc[g][mt][3] = b;
      }
    }
#pragma unroll
    for (int mt = 0; mt < 4; ++mt) {
      bf16x8 xf = zfrag;
      if (q == 0) xf = *(const bf16x8*)(xsrc + (t * 64 + mt * 16 + c) * 8);
#pragma unroll
      for (int g = 0; g < 4; ++g)
        acc[g][mt] = __builtin_amdgcn_mfma_f32_16x16x32_bf16(xf, wxp[g], acc[g][mt], 0, 0, 0);
    }
#pragma unroll
    for (int kc = 0; kc < 2; ++kc)
#pragma unroll
      for (int mt = 0; mt < 4; ++mt) {
        bf16x8 hf = *(const bf16x8*)(hb + (kc * 4 + mt) * 512 + lane * 8);
#pragma unroll
        for (int g = 0; g < 4; ++g)
          acc[g][mt] = __builtin_amdgcn_mfma_f32_16x16x32_bf16(hf, wh[g][kc], acc[g][mt], 0, 0, 0);
      }
    epilogue(acc, hb, cs);
  };

  // ---- encoder ----
  loadPad(eWih0, 6, wxL0);
  loadFull(eWhh0, whL0);
  loadFull(eWih1, wxL1);
  loadFull(eWhh1, whL1);
  loadBias(ebih0, ebhh0, bs0);
  loadBias(ebih1, ebhh1, bs1);

  __syncthreads();

#pragma unroll 1
  for (int t = 0; t < SEQ; ++t) {
    cellP(xbuf, t, wxL0, whL0, hb0, bs0, cs0);
    cellF(hb0, wxL1, whL1, hb1, bs1, cs1);
  }

  // ---- decoder weights ----
  loadPad(dWih0, 2, wxL0);
  loadFull(dWhh0, whL0);
  loadFull(dWih1, wxL1);
  loadFull(dWhh1, whL1);
  loadBias(dbih0, dbhh0, bs0);
  loadBias(dbih1, dbhh1, bs1);

  bf16x8 wlin[2];
#pragma unroll
  for (int kc = 0; kc < 2; ++kc) {
    bf16x8 f = zfrag;
    if (c < 2) {
      const float* p = linW + c * 64 + kc * 32 + q * 8;
#pragma unroll
      for (int j = 0; j < 8; ++j) f[j] = bfc(p[j]);  // unscaled
    }
    wlin[kc] = f;
  }
  const float lb = (c < 2) ? linb[c] : 0.0f;

  {
    float s0 = stok[0], s1 = stok[1];
    for (int i = tid; i < 64; i += 256) {
      obuf[i * 8 + 0] = bfc(s0);
      obuf[i * 8 + 1] = bfc(s1);
#pragma unroll
      for (int j = 2; j < 8; ++j) obuf[i * 8 + j] = (__bf16)0.0f;
    }
  }
  __syncthreads();

  // ---- decoder ----
#pragma unroll 1
  for (int t = 0; t < TDEC; ++t) {
    cellP(obuf, 0, wxL0, whL0, hb0, bs0, cs0);
    cellF(hb0, wxL1, whL1, hb1, bs1, cs1);
    // linear head: wave w handles M-tile mt=w (16 rows)
    {
      f32x4 oa;
      oa[0] = lb; oa[1] = lb; oa[2] = lb; oa[3] = lb;
#pragma unroll
      for (int kc = 0; kc < 2; ++kc) {
        bf16x8 hf = *(const bf16x8*)(hb1 + (kc * 4 + w) * 512 + lane * 8);
        oa = __builtin_amdgcn_mfma_f32_16x16x32_bf16(hf, wlin[kc], oa, 0, 0, 0);
      }
      if (c < 2) {
#pragma unroll
        for (int r = 0; r < 4; ++r) {
          int row = w * 16 + q * 4 + r;
          float v = oa[r];
          out[(rowbase + row) * 120 + t * 2 + c] = v;
          obuf[row * 8 + c] = bfc(v);
        }
      }
    }
    __syncthreads();   // obuf/out visible before next step's cellP reads obuf
  }
}

extern "C" void kernel_launch(void* const* d_in, const int* in_sizes, int n_in,
                              void* d_out, int out_size, void* d_ws, size_t ws_size,
                              hipStream_t stream) {
  (void)in_sizes; (void)n_in; (void)d_ws; (void)ws_size; (void)out_size;
  const float* p[20];
  for (int i = 0; i < 20; ++i) p[i] = (const float*)d_in[i];
  dim3 grid(512), block(256);
  hipLaunchKernelGGL(lstm_s2s, grid, block, 0, stream,
                     p[0], p[1], p[2], p[3], p[4], p[5], p[6], p[7], p[8], p[9],
                     p[10], p[11], p[12], p[13], p[14], p[15], p[16], p[17], p[18], p[19],
                     (float*)d_out);
}

// Round 2
// 1164.722 us; speedup vs baseline: 1.0612x; 1.0612x over previous
//
#include <hip/hip_runtime.h>
#include <stdint.h>

typedef float f32x4 __attribute__((ext_vector_type(4)));
typedef __bf16 bf16x8 __attribute__((ext_vector_type(8)));

#define SEQ 50
#define TDEC 60
#define XCH 10   // encoder x-history steps staged per chunk

static __device__ __forceinline__ float ex2(float x) { return __builtin_amdgcn_exp2f(x); }
static __device__ __forceinline__ float frcp_(float x) { return __builtin_amdgcn_rcpf(x); }
static __device__ __forceinline__ __bf16 bfc(float x) { return (__bf16)x; }

// 512 blocks x 256 threads; block owns 64 batch rows for the whole sequence.
// Wave w owns hidden-slice u in [16w,16w+16) => gate n-tiles {w, w+4, w+8, w+12}.
// h LDS layout frag-major [kc][mt][quad][m16][8]: A-frag read = base + lane*16B.
// Double-buffered hb => 1 barrier per cell. Layer-0 bias rides the x pad slot
// (x[6]=1.0, weight row 6 = scaled bias) so cellP accumulators start from a
// shared zero C-frag (no per-cell acc init).
__global__ __launch_bounds__(256, 2) void lstm_s2s(
    const float* __restrict__ hist,
    const float* __restrict__ eWih0, const float* __restrict__ eWhh0,
    const float* __restrict__ ebih0, const float* __restrict__ ebhh0,
    const float* __restrict__ eWih1, const float* __restrict__ eWhh1,
    const float* __restrict__ ebih1, const float* __restrict__ ebhh1,
    const float* __restrict__ dWih0, const float* __restrict__ dWhh0,
    const float* __restrict__ dbih0, const float* __restrict__ dbhh0,
    const float* __restrict__ dWih1, const float* __restrict__ dWhh1,
    const float* __restrict__ dbih1, const float* __restrict__ dbhh1,
    const float* __restrict__ linW, const float* __restrict__ linb,
    const float* __restrict__ stok,
    float* __restrict__ out)
{
  __shared__ __bf16 xch[XCH * 64 * 8];    // [tloc][row][8] (6 real + 1.0 + 0)
  __shared__ __bf16 hb0[2][4096];         // [kc][mt][q][m16][8], double-buffered
  __shared__ __bf16 hb1[2][4096];
  __shared__ __bf16 obuf[64 * 8];         // decoder feedback, slot6 = 1.0
  __shared__ __bf16 wx0s[4 * 4 * 64 * 8]; // layer-0 input-weight B-frags [w][g][lane][8]
  __shared__ __bf16 wlc[128];             // lin head weights [kc][c][32k]

  const int tid = threadIdx.x;
  const int lane = tid & 63;
  const int w = tid >> 6;
  const int c = lane & 15;
  const int q = lane >> 4;
  const long rowbase = (long)blockIdx.x * 64;
  const float* eg = hist + rowbase * 3000;   // agent 0 slice; 3000 = A*S*IN

  bf16x8 zfrag;
#pragma unroll
  for (int j = 0; j < 8; ++j) zfrag[j] = (__bf16)0.0f;
  f32x4 zero4;
  zero4[0] = 0.f; zero4[1] = 0.f; zero4[2] = 0.f; zero4[3] = 0.f;

  // gate scales: i,f,o -> sigmoid via exp2(-x*log2e); g -> tanh via exp2(2x*log2e)
  const float GS[4] = {-1.442695041f, -1.442695041f, 2.885390082f, -1.442695041f};

  bf16x8 whL0[4][2], wxL1[4][2], whL1[4][2];
  float bs1[4];

  auto loadFull = [&](const float* W, bf16x8 (*dst)[2]) {
#pragma unroll
    for (int g = 0; g < 4; ++g)
#pragma unroll
      for (int kc = 0; kc < 2; ++kc) {
        const float* p = W + ((g * 4 + w) * 16 + c) * 64 + kc * 32 + q * 8;
        f32x4 a = *(const f32x4*)p;
        f32x4 b = *(const f32x4*)(p + 4);
        bf16x8 f;
        f[0] = bfc(GS[g] * a[0]); f[1] = bfc(GS[g] * a[1]);
        f[2] = bfc(GS[g] * a[2]); f[3] = bfc(GS[g] * a[3]);
        f[4] = bfc(GS[g] * b[0]); f[5] = bfc(GS[g] * b[1]);
        f[6] = bfc(GS[g] * b[2]); f[7] = bfc(GS[g] * b[3]);
        dst[g][kc] = f;
      }
  };
  auto loadBias = [&](const float* bi, const float* bh, float* bs) {
#pragma unroll
    for (int g = 0; g < 4; ++g) {
      int n = g * 64 + w * 16 + c;
      bs[g] = GS[g] * (bi[n] + bh[n]);
    }
  };
  // stage layer-0 input weights (padded to K=8, bias in slot 6) into LDS
  auto stageWx0 = [&](const float* W, int Kin, const float* bi, const float* bh) {
    for (int s = tid; s < 1024; s += 256) {
      int w2 = s >> 8;
      int g = (s >> 6) & 3;
      int ln = s & 63;
      int cc = ln & 15, qq = ln >> 4;
      float gs = (g == 2) ? 2.885390082f : -1.442695041f;
      __bf16* dst = wx0s + s * 8;
      int row = (g * 4 + w2) * 16 + cc;
      if (qq == 0) {
        for (int j = 0; j < 8; ++j) {
          float v = 0.0f;
          if (j < Kin) v = W[row * Kin + j];
          else if (j == 6) v = bi[row] + bh[row];
          dst[j] = bfc(gs * v);
        }
      } else {
        for (int j = 0; j < 8; ++j) dst[j] = (__bf16)0.0f;
      }
    }
  };
  auto stageX = [&](int t0) {
    for (int i = tid; i < XCH * 64 * 8; i += 256) {
      int k = i & 7;
      int row = (i >> 3) & 63;
      int tl = i >> 9;
      float v;
      if (k < 6) v = eg[row * 3000 + (t0 + tl) * 6 + k];
      else v = (k == 6) ? 1.0f : 0.0f;
      xch[i] = bfc(v);
    }
  };

  // h-write address constant (C-layout -> frag-major LDS)
  const int u = w * 16 + c;
  const int wconst = (u >> 5) * 2048 + ((u >> 3) & 3) * 128 + q * 32 + (u & 7);

  float cs0[16], cs1[16];
#pragma unroll
  for (int i = 0; i < 16; ++i) { cs0[i] = 0.0f; cs1[i] = 0.0f; }

  auto epilogue = [&](f32x4 (*acc)[4], __bf16* hnxt, float* cs) {
#pragma unroll
    for (int mt = 0; mt < 4; ++mt)
#pragma unroll
      for (int r = 0; r < 4; ++r) {
        float eI = ex2(acc[0][mt][r]);   // e^{-i}
        float eF = ex2(acc[1][mt][r]);   // e^{-f}
        float eG = ex2(acc[2][mt][r]);   // e^{2g}
        float eO = ex2(acc[3][mt][r]);   // e^{-o}
        float cc = cs[mt * 4 + r];
        float c2 = frcp_(1.0f + eF) * cc +
                   (eG - 1.0f) * frcp_((1.0f + eI) * (eG + 1.0f));
        float eC = ex2(2.885390082f * c2);
        float h2 = (eC - 1.0f) * frcp_((1.0f + eO) * (eC + 1.0f));
        cs[mt * 4 + r] = c2;
        hnxt[wconst + mt * 512 + r * 8] = bfc(h2);
      }
    __syncthreads();
  };

  // layer-0 cell: small padded x (K=8 incl bias slot), h from hcur, writes hnxt
  auto cellP = [&](const __bf16* xsrc, const __bf16* hcur, __bf16* hnxt, float* cs) {
    bf16x8 wxf[4];
#pragma unroll
    for (int g = 0; g < 4; ++g)
      wxf[g] = *(const bf16x8*)(wx0s + (w * 256 + g * 64 + lane) * 8);
    f32x4 acc[4][4];
#pragma unroll
    for (int mt = 0; mt < 4; ++mt) {
      bf16x8 xf = zfrag;
      if (q == 0) xf = *(const bf16x8*)(xsrc + (mt * 16 + c) * 8);
#pragma unroll
      for (int g = 0; g < 4; ++g)
        acc[g][mt] = __builtin_amdgcn_mfma_f32_16x16x32_bf16(xf, wxf[g], zero4, 0, 0, 0),
        (void)0;
    }
    // note: first mfma above must accumulate into zero then chain; redo properly:
    // (the loop above already used zero4 as C for each g at its first mt step —
    //  but we need per-(g,mt) chains; the assignment pattern below is the real one)
#pragma unroll
    for (int kc = 0; kc < 2; ++kc)
#pragma unroll
      for (int mt = 0; mt < 4; ++mt) {
        bf16x8 hf = *(const bf16x8*)(hcur + (kc * 4 + mt) * 512 + lane * 8);
#pragma unroll
        for (int g = 0; g < 4; ++g)
          acc[g][mt] = __builtin_amdgcn_mfma_f32_16x16x32_bf16(hf, whL0[g][kc], acc[g][mt], 0, 0, 0);
      }
    epilogue(acc, hnxt, cs);
  };

  // layer-1 cell: x = h0 (full K=64), h from hcur, writes hnxt
  auto cellF = [&](const __bf16* xcur, const __bf16* hcur, __bf16* hnxt, float* cs) {
    f32x4 acc[4][4];
#pragma unroll
    for (int g = 0; g < 4; ++g) {
      float b = bs1[g];
#pragma unroll
      for (int mt = 0; mt < 4; ++mt) {
        acc[g][mt][0] = b; acc[g][mt][1] = b; acc[g][mt][2] = b; acc[g][mt][3] = b;
      }
    }
#pragma unroll
    for (int kc = 0; kc < 2; ++kc)
#pragma unroll
      for (int mt = 0; mt < 4; ++mt) {
        bf16x8 xf = *(const bf16x8*)(xcur + (kc * 4 + mt) * 512 + lane * 8);
#pragma unroll
        for (int g = 0; g < 4; ++g)
          acc[g][mt] = __builtin_amdgcn_mfma_f32_16x16x32_bf16(xf, wxL1[g][kc], acc[g][mt], 0, 0, 0);
      }
#pragma unroll
    for (int kc = 0; kc < 2; ++kc)
#pragma unroll
      for (int mt = 0; mt < 4; ++mt) {
        bf16x8 hf = *(const bf16x8*)(hcur + (kc * 4 + mt) * 512 + lane * 8);
#pragma unroll
        for (int g = 0; g < 4; ++g)
          acc[g][mt] = __builtin_amdgcn_mfma_f32_16x16x32_bf16(hf, whL1[g][kc], acc[g][mt], 0, 0, 0);
      }
    epilogue(acc, hnxt, cs);
  };

  // ---- init: zero h state buffers [0] ----
  for (int i = tid; i < 2048; i += 256) {
    ((unsigned int*)hb0[0])[i] = 0u;
    ((unsigned int*)hb1[0])[i] = 0u;
  }

  // ---- encoder ----
  stageWx0(eWih0, 6, ebih0, ebhh0);
  loadFull(eWhh0, whL0);
  loadFull(eWih1, wxL1);
  loadFull(eWhh1, whL1);
  loadBias(ebih1, ebhh1, bs1);

  int pc = 0;
#pragma unroll 1
  for (int t = 0; t < SEQ; ++t) {
    if ((t % XCH) == 0) {
      stageX(t);
      __syncthreads();
    }
    cellP(xch + (t % XCH) * 512, hb0[pc], hb0[pc ^ 1], cs0);
    cellF(hb0[pc ^ 1], hb1[pc], hb1[pc ^ 1], cs1);
    pc ^= 1;
  }

  // ---- decoder setup ----
  stageWx0(dWih0, 2, dbih0, dbhh0);
  loadFull(dWhh0, whL0);
  loadFull(dWih1, wxL1);
  loadFull(dWhh1, whL1);
  loadBias(dbih1, dbhh1, bs1);

  for (int i = tid; i < 128; i += 256) {
    int kc = i >> 6, cc = (i >> 5) & 1, kk = i & 31;
    wlc[(kc * 2 + cc) * 32 + kk] = bfc(linW[cc * 64 + kc * 32 + kk]);
  }
  const float lb = (c < 2) ? linb[c] : 0.0f;
  {
    float s0 = stok[0], s1 = stok[1];
    for (int i = tid; i < 64; i += 256) {
      obuf[i * 8 + 0] = bfc(s0);
      obuf[i * 8 + 1] = bfc(s1);
      obuf[i * 8 + 2] = (__bf16)0.0f;
      obuf[i * 8 + 3] = (__bf16)0.0f;
      obuf[i * 8 + 4] = (__bf16)0.0f;
      obuf[i * 8 + 5] = (__bf16)0.0f;
      obuf[i * 8 + 6] = (__bf16)1.0f;   // bias slot
      obuf[i * 8 + 7] = (__bf16)0.0f;
    }
  }
  __syncthreads();

  // ---- decoder ----
#pragma unroll 1
  for (int t = 0; t < TDEC; ++t) {
    cellP(obuf, hb0[pc], hb0[pc ^ 1], cs0);
    cellF(hb0[pc ^ 1], hb1[pc], hb1[pc ^ 1], cs1);
    {
      f32x4 oa;
      oa[0] = lb; oa[1] = lb; oa[2] = lb; oa[3] = lb;
#pragma unroll
      for (int kc = 0; kc < 2; ++kc) {
        bf16x8 hf = *(const bf16x8*)(hb1[pc ^ 1] + (kc * 4 + w) * 512 + lane * 8);
        bf16x8 wf = zfrag;
        if (c < 2) wf = *(const bf16x8*)(wlc + (kc * 2 + c) * 32 + q * 8);
        oa = __builtin_amdgcn_mfma_f32_16x16x32_bf16(hf, wf, oa, 0, 0, 0);
      }
      if (c < 2) {
#pragma unroll
        for (int r = 0; r < 4; ++r) {
          int row = w * 16 + q * 4 + r;
          float v = oa[r];
          out[(rowbase + row) * 120 + t * 2 + c] = v;
          obuf[row * 8 + c] = bfc(v);
        }
      }
    }
    __syncthreads();
    pc ^= 1;
  }
}

extern "C" void kernel_launch(void* const* d_in, const int* in_sizes, int n_in,
                              void* d_out, int out_size, void* d_ws, size_t ws_size,
                              hipStream_t stream) {
  (void)in_sizes; (void)n_in; (void)d_ws; (void)ws_size; (void)out_size;
  const float* p[20];
  for (int i = 0; i < 20; ++i) p[i] = (const float*)d_in[i];
  dim3 grid(512), block(256);
  hipLaunchKernelGGL(lstm_s2s, grid, block, 0, stream,
                     p[0], p[1], p[2], p[3], p[4], p[5], p[6], p[7], p[8], p[9],
                     p[10], p[11], p[12], p[13], p[14], p[15], p[16], p[17], p[18], p[19],
                     (float*)d_out);
}

// Round 3
// 1044.841 us; speedup vs baseline: 1.1830x; 1.1147x over previous
//
#include <hip/hip_runtime.h>
#include <stdint.h>

typedef float f32x4 __attribute__((ext_vector_type(4)));
typedef __bf16 bf16x8 __attribute__((ext_vector_type(8)));
typedef __bf16 bf16x4 __attribute__((ext_vector_type(4)));

#define SEQ 50
#define TDEC 60

static __device__ __forceinline__ float ex2(float x){return __builtin_amdgcn_exp2f(x);}
static __device__ __forceinline__ float frcp_(float x){return __builtin_amdgcn_rcpf(x);}
static __device__ __forceinline__ __bf16 bfc(float x){return (__bf16)x;}

// 2048 blocks x 256 thr (4 waves), 16 batch rows/block, full 110-step sequence.
// Operand-swapped MFMA: A = weights (M=gate dim), B = state (N=batch).
// C layout: col=lane&15=batch row, rows=q*4+r = 4 CONSECUTIVE hidden units
//   -> epilogue writes one packed ds_write_b64 per cell (no 8-way conflicts).
// Wave w owns hidden slice [16w,16w+16): gate M-tiles {w, w+4, w+8, w+12}.
// h LDS layout [kc][q_r][m16][j8]; B-frag read addr = lane*16B (conflict-free).
// Layer-0 bias rides x pad slot 6 (x[6]=1); layer-1 bias via k==0 bias-column
// MFMA from LDS frags -> no accumulator init VALU at all (C starts at zero4).
// Registers: weights 96 + acc 16 + cs 8 + misc -> target <=168 for 3 waves/SIMD.
__global__ __launch_bounds__(256,3) void lstm_s2s(
    const float* __restrict__ hist,
    const float* __restrict__ eWih0, const float* __restrict__ eWhh0,
    const float* __restrict__ ebih0, const float* __restrict__ ebhh0,
    const float* __restrict__ eWih1, const float* __restrict__ eWhh1,
    const float* __restrict__ ebih1, const float* __restrict__ ebhh1,
    const float* __restrict__ dWih0, const float* __restrict__ dWhh0,
    const float* __restrict__ dbih0, const float* __restrict__ dbhh0,
    const float* __restrict__ dWih1, const float* __restrict__ dWhh1,
    const float* __restrict__ dbih1, const float* __restrict__ dbhh1,
    const float* __restrict__ linW, const float* __restrict__ linb,
    const float* __restrict__ stok,
    float* __restrict__ out)
{
  __shared__ __bf16 xch[SEQ*16*8];     // [t][row16][8] (6 real, slot6=1.0 bias, slot7=0)
  __shared__ __bf16 hb0[2][1024];      // [kc][q_r][m16][j8], double-buffered
  __shared__ __bf16 hb1[2][1024];
  __shared__ __bf16 wx0s[4*4*17*8];    // L0 x-weight A-frags [w][g][row17][8], row16=0
  __shared__ __bf16 bf1s[4*4*17*8];    // L1 bias-column A-frags, same addressing
  __shared__ __bf16 wlc[2*3*4*8];      // head A-frags [kc][row(0,1,zero)][q][8]
  __shared__ __bf16 obuf[16*8];        // decoder feedback [row16][8], slot6=1.0

  const int tid = threadIdx.x;
  const int lane = tid & 63;
  const int w = tid >> 6;
  const int c = lane & 15;
  const int q = lane >> 4;
  const int rsel = (q == 0) ? c : 16;          // zero-row redirect for q>0
  const long rowbase = (long)blockIdx.x * 16;
  const float* eg = hist + rowbase * 3000;     // agent-0 slice; 3000 = A*S*IN

  union { f32x4 f; bf16x8 h; } Z;
  Z.f[0]=0.f; Z.f[1]=0.f; Z.f[2]=0.f; Z.f[3]=0.f;
  const f32x4 zero4 = Z.f;
  const bf16x8 zfrag = Z.h;
  bf16x8 onef = zfrag;                         // B-frag of constant-1 at k==0
  if (q == 0) onef[0] = (__bf16)1.0f;

  const float GS[4] = {-1.442695041f,-1.442695041f,2.885390082f,-1.442695041f};

  // ---- prologue staging ----
  for (int i = tid; i < 16*300; i += 256) {
    int row = i / 300, o = i - row*300;
    int t = o / 6, k = o - t*6;
    xch[(t*16+row)*8 + k] = bfc(eg[row*3000 + o]);
  }
  for (int i = tid; i < 16*SEQ; i += 256) {
    xch[i*8+6] = (__bf16)1.0f;
    xch[i*8+7] = (__bf16)0.0f;
  }
  for (int i = tid; i < 512; i += 256) {
    ((uint32_t*)hb0[0])[i] = 0u;
    ((uint32_t*)hb1[0])[i] = 0u;
  }

  auto stageWx0 = [&](const float* W, int Kin, const float* bi, const float* bh) {
    for (int i = tid; i < 272; i += 256) {
      int w2 = i / 68, rem = i - w2*68;
      int g = rem / 17, row = rem - g*17;
      __bf16* dst = wx0s + i*8;
      if (row < 16) {
        int gate = (g*4 + w2)*16 + row;
        float gs = (g==2) ? 2.885390082f : -1.442695041f;
        for (int j = 0; j < 8; ++j) {
          float v = 0.f;
          if (j < Kin) v = W[gate*Kin + j];
          else if (j == 6) v = bi[gate] + bh[gate];
          dst[j] = bfc(gs*v);
        }
      } else {
        for (int j = 0; j < 8; ++j) dst[j] = (__bf16)0.f;
      }
    }
  };
  auto stageBf1 = [&](const float* bi, const float* bh) {
    for (int i = tid; i < 272; i += 256) {
      int w2 = i / 68, rem = i - w2*68;
      int g = rem / 17, row = rem - g*17;
      __bf16* dst = bf1s + i*8;
      float v = 0.f;
      if (row < 16) {
        int gate = (g*4 + w2)*16 + row;
        float gs = (g==2) ? 2.885390082f : -1.442695041f;
        v = gs*(bi[gate] + bh[gate]);
      }
      dst[0] = bfc(v);
      for (int j = 1; j < 8; ++j) dst[j] = (__bf16)0.f;
    }
  };

  bf16x8 whL0[4][2], wxL1[4][2], whL1[4][2];
  auto loadFull = [&](const float* W, bf16x8 (*dst)[2]) {
#pragma unroll
    for (int g = 0; g < 4; ++g)
#pragma unroll
      for (int kc = 0; kc < 2; ++kc) {
        const float* p = W + ((g*4 + w)*16 + c)*64 + kc*32 + q*8;
        f32x4 a = *(const f32x4*)p;
        f32x4 b = *(const f32x4*)(p + 4);
        bf16x8 f;
        f[0]=bfc(GS[g]*a[0]); f[1]=bfc(GS[g]*a[1]);
        f[2]=bfc(GS[g]*a[2]); f[3]=bfc(GS[g]*a[3]);
        f[4]=bfc(GS[g]*b[0]); f[5]=bfc(GS[g]*b[1]);
        f[6]=bfc(GS[g]*b[2]); f[7]=bfc(GS[g]*b[3]);
        dst[g][kc] = f;
      }
  };

  // epilogue write address: hidden u = 16w + q*4 + r, r=0..3 contiguous j
  const int wconst = (w>>1)*512 + (((w&1)<<1) | (q>>1))*128 + c*8 + (q&1)*4;

  float cs0[4], cs1[4];
#pragma unroll
  for (int i = 0; i < 4; ++i) { cs0[i] = 0.f; cs1[i] = 0.f; }

  auto epilogue = [&](f32x4* a, float* cs, __bf16* hnxt) {
    bf16x4 hv;
#pragma unroll
    for (int r = 0; r < 4; ++r) {
      float eI = ex2(a[0][r]);          // e^{-i}
      float eF = ex2(a[1][r]);          // e^{-f}
      float eG = ex2(a[2][r]);          // e^{2g}
      float eO = ex2(a[3][r]);          // e^{-o}
      float P  = (1.f+eI)*(eG+1.f);
      float tt = 1.f+eF;
      float D  = frcp_(tt*P);           // merged rcp: c/(1+eF) + (eG-1)/P
      float c2 = (cs[r]*P + (eG-1.f)*tt)*D;
      float eC = ex2(2.885390082f*c2);
      float h2 = (eC-1.f)*frcp_((1.f+eO)*(eC+1.f));
      cs[r] = c2;
      hv[r] = bfc(h2);
    }
    *(bf16x4*)(hnxt + wconst) = hv;     // one 8B packed write
    __syncthreads();
  };

  // layer-0 cell: padded x (K=8 incl bias slot), weights from LDS frags
  auto cellP = [&](const __bf16* xsrc, const __bf16* hcur, __bf16* hnxt, float* cs) {
    bf16x8 xf = zfrag;
    if (q == 0) xf = *(const bf16x8*)(xsrc + c*8);
    bf16x8 hf0 = *(const bf16x8*)(hcur + lane*8);
    bf16x8 hf1 = *(const bf16x8*)(hcur + 512 + lane*8);
    f32x4 a[4];
#pragma unroll
    for (int g = 0; g < 4; ++g) {
      bf16x8 wxf = *(const bf16x8*)(wx0s + ((w*4+g)*17 + rsel)*8);
      a[g] = __builtin_amdgcn_mfma_f32_16x16x32_bf16(wxf, xf, zero4, 0,0,0);
    }
#pragma unroll
    for (int g = 0; g < 4; ++g)
      a[g] = __builtin_amdgcn_mfma_f32_16x16x32_bf16(whL0[g][0], hf0, a[g], 0,0,0);
#pragma unroll
    for (int g = 0; g < 4; ++g)
      a[g] = __builtin_amdgcn_mfma_f32_16x16x32_bf16(whL0[g][1], hf1, a[g], 0,0,0);
    epilogue(a, cs, hnxt);
  };

  // layer-1 cell: x = new h0 (K=64), bias via k==0 column MFMA
  auto cellF = [&](const __bf16* xcur, const __bf16* hcur, __bf16* hnxt, float* cs) {
    bf16x8 xf0 = *(const bf16x8*)(xcur + lane*8);
    bf16x8 xf1 = *(const bf16x8*)(xcur + 512 + lane*8);
    bf16x8 hf0 = *(const bf16x8*)(hcur + lane*8);
    bf16x8 hf1 = *(const bf16x8*)(hcur + 512 + lane*8);
    f32x4 a[4];
#pragma unroll
    for (int g = 0; g < 4; ++g) {
      bf16x8 bfr = *(const bf16x8*)(bf1s + ((w*4+g)*17 + rsel)*8);
      a[g] = __builtin_amdgcn_mfma_f32_16x16x32_bf16(bfr, onef, zero4, 0,0,0);
    }
#pragma unroll
    for (int g = 0; g < 4; ++g)
      a[g] = __builtin_amdgcn_mfma_f32_16x16x32_bf16(wxL1[g][0], xf0, a[g], 0,0,0);
#pragma unroll
    for (int g = 0; g < 4; ++g)
      a[g] = __builtin_amdgcn_mfma_f32_16x16x32_bf16(wxL1[g][1], xf1, a[g], 0,0,0);
#pragma unroll
    for (int g = 0; g < 4; ++g)
      a[g] = __builtin_amdgcn_mfma_f32_16x16x32_bf16(whL1[g][0], hf0, a[g], 0,0,0);
#pragma unroll
    for (int g = 0; g < 4; ++g)
      a[g] = __builtin_amdgcn_mfma_f32_16x16x32_bf16(whL1[g][1], hf1, a[g], 0,0,0);
    epilogue(a, cs, hnxt);
  };

  // ---- encoder ----
  stageWx0(eWih0, 6, ebih0, ebhh0);
  stageBf1(ebih1, ebhh1);
  loadFull(eWhh0, whL0);
  loadFull(eWih1, wxL1);
  loadFull(eWhh1, whL1);
  __syncthreads();

  int pc = 0;
#pragma unroll 1
  for (int t = 0; t < SEQ; ++t) {
    cellP(xch + t*128, hb0[pc], hb0[pc^1], cs0);
    cellF(hb0[pc^1], hb1[pc], hb1[pc^1], cs1);
    pc ^= 1;
  }

  // ---- decoder setup ----
  stageWx0(dWih0, 2, dbih0, dbhh0);
  stageBf1(dbih1, dbhh1);
  loadFull(dWhh0, whL0);
  loadFull(dWih1, wxL1);
  loadFull(dWhh1, whL1);
  for (int i = tid; i < 24; i += 256) {
    int kc = i / 12, rem = i - kc*12;
    int row = rem / 4, q2 = rem - row*4;
    __bf16* dst = wlc + i*8;
    for (int j = 0; j < 8; ++j)
      dst[j] = (row < 2) ? bfc(linW[row*64 + kc*32 + q2*8 + j]) : (__bf16)0.f;
  }
  {
    float s0 = stok[0], s1 = stok[1];
    for (int i = tid; i < 16; i += 256) {
      obuf[i*8+0] = bfc(s0);
      obuf[i*8+1] = bfc(s1);
      obuf[i*8+2] = (__bf16)0.f;
      obuf[i*8+3] = (__bf16)0.f;
      obuf[i*8+4] = (__bf16)0.f;
      obuf[i*8+5] = (__bf16)0.f;
      obuf[i*8+6] = (__bf16)1.0f;      // bias slot
      obuf[i*8+7] = (__bf16)0.f;
    }
  }
  const float lb0 = linb[0], lb1 = linb[1];
  __syncthreads();

  // ---- decoder ----
#pragma unroll 1
  for (int t = 0; t < TDEC; ++t) {
    cellP(obuf, hb0[pc], hb0[pc^1], cs0);
    cellF(hb0[pc^1], hb1[pc], hb1[pc^1], cs1);
    if (w == 0) {                       // head: C[m=out-dim][n=batch]
      const __bf16* h1 = hb1[pc^1];
      bf16x8 xf0 = *(const bf16x8*)(h1 + lane*8);
      bf16x8 xf1 = *(const bf16x8*)(h1 + 512 + lane*8);
      int hr = (c < 2) ? c : 2;
      bf16x8 wl0 = *(const bf16x8*)(wlc + hr*32 + q*8);
      bf16x8 wl1 = *(const bf16x8*)(wlc + 96 + hr*32 + q*8);
      f32x4 oa = __builtin_amdgcn_mfma_f32_16x16x32_bf16(wl0, xf0, zero4, 0,0,0);
      oa = __builtin_amdgcn_mfma_f32_16x16x32_bf16(wl1, xf1, oa, 0,0,0);
      if (q == 0) {                     // rows m=0,1 live in quad 0, regs 0,1
        float v0 = oa[0] + lb0, v1 = oa[1] + lb1;
        float2 vv; vv.x = v0; vv.y = v1;
        *(float2*)(out + (rowbase + c)*120 + t*2) = vv;
        obuf[c*8+0] = bfc(v0);
        obuf[c*8+1] = bfc(v1);
      }
    }
    __syncthreads();
    pc ^= 1;
  }
}

extern "C" void kernel_launch(void* const* d_in, const int* in_sizes, int n_in,
                              void* d_out, int out_size, void* d_ws, size_t ws_size,
                              hipStream_t stream) {
  (void)in_sizes; (void)n_in; (void)d_ws; (void)ws_size; (void)out_size;
  const float* p[20];
  for (int i = 0; i < 20; ++i) p[i] = (const float*)d_in[i];
  dim3 grid(2048), block(256);
  hipLaunchKernelGGL(lstm_s2s, grid, block, 0, stream,
                     p[0], p[1], p[2], p[3], p[4], p[5], p[6], p[7], p[8], p[9],
                     p[10], p[11], p[12], p[13], p[14], p[15], p[16], p[17], p[18], p[19],
                     (float*)d_out);
}